// Round 13
// baseline (32.070 us; speedup 1.0000x reference)
//
#include <hip/hip_runtime.h>
#include <math.h>

// y_t = clamp(y_{t-1}, x_t, x_t+1): play operator as associative clamp-scan.
// compose(l, r) = "apply l first, then r". min/max/med3-only => exact =>
// any regrouping is bit-identical (deterministic).
//
// COLLAPSE PROPERTY: composed windows contract and width-0 is absorbing.
// Element 0's window is (p0,p0) -- width 0 -- so ANY prefix reaching element
// 0 is collapsed. Each block recomputes its exact incoming value from the
// RAW INPUT halo: walk backwards in 256-element chunks, composing chunk
// aggregates until the suffix collapses (guaranteed at element 0; typically
// 1 chunk for this data). NO inter-block communication (rounds 2/10/11:
// cross-XCD sync through non-coherent L2s costs 2-6x).
//
// EPT=4: each thread owns exactly one float4 -> loads AND stores are
// lane-contiguous (1 KB/wave/instruction), no LDS transpose (round 12's
// EPT=16 version spent ~5 us on 32 scalar LDS ops/thread).

#define TPB 256
#define EPT 4
#define EPB (TPB * EPT)   // 1024 elements per block -> nb = 16385 for T=2^24
#define NW  (TPB / 64)
#define HCH TPB           // halo chunk: 1 element per thread

struct Pair { float a, b; };

__device__ __forceinline__ float med3f(float x, float lo, float hi) {
    return __builtin_amdgcn_fmed3f(x, lo, hi);   // clamp(x, lo, hi), lo<=hi
}
__device__ __forceinline__ Pair compose(Pair l, Pair r) {
    Pair o; o.a = med3f(l.a, r.a, r.b); o.b = med3f(l.b, r.a, r.b); return o;
}
__device__ __forceinline__ Pair ident() {
    Pair p; p.a = -INFINITY; p.b = INFINITY; return p;
}

__global__ __launch_bounds__(TPB)
void k_scan(const float* __restrict__ in, const float* __restrict__ kptr,
            float* __restrict__ out, int n) {
    const int tid  = threadIdx.x, lane = tid & 63, wid = tid >> 6;
    const int vid  = blockIdx.x;
    const int tile0 = vid * EPB;
    const int base  = tile0 + tid * EPT;
    const float k   = kptr[0];
    const bool blockFull = (tile0 + EPB <= n);   // uniform across block

    __shared__ Pair wS[NW];                      // block-scan wave aggs
    __shared__ Pair wC[NW];                      // halo-chunk wave aggs

    // ---- 1) one float4 per thread + per-element inclusive windows ---------
    float ta[EPT], tb[EPT];                      // static indexing only
    {
        float a = -INFINITY, b = INFINITY;
        if (blockFull) {
            float4 f = *reinterpret_cast<const float4*>(in + base);
            float xv[4] = {f.x, f.y, f.z, f.w};
            #pragma unroll
            for (int j = 0; j < 4; ++j) {
                float lo = xv[j] * k, hi = lo + 1.0f;
                if (j == 0 && base == 0) { lo = xv[0]; hi = xv[0]; }  // p0
                a = med3f(a, lo, hi);
                b = med3f(b, lo, hi);
                ta[j] = a; tb[j] = b;
            }
        } else {
            #pragma unroll
            for (int j = 0; j < EPT; ++j) {
                if (base + j < n) {
                    float x = in[base + j];
                    float lo = x * k, hi = lo + 1.0f;
                    if (j == 0 && base == 0) { lo = x; hi = x; }
                    a = med3f(a, lo, hi);
                    b = med3f(b, lo, hi);
                }
                ta[j] = a; tb[j] = b;
            }
        }
    }

    // ---- 2) block scan of thread aggregates -> exclusive window ex --------
    Pair w; w.a = ta[EPT - 1]; w.b = tb[EPT - 1];
    #pragma unroll
    for (int off = 1; off < 64; off <<= 1) {
        Pair u; u.a = __shfl_up(w.a, off); u.b = __shfl_up(w.b, off);
        if (lane >= off) w = compose(u, w);
    }
    if (lane == 63) wS[wid] = w;
    __syncthreads();
    Pair wpre = ident();
    #pragma unroll
    for (int i = 0; i < NW; ++i) if (i < wid) wpre = compose(wpre, wS[i]);
    Pair up; up.a = __shfl_up(w.a, 1); up.b = __shfl_up(w.b, 1);
    Pair ex = (lane == 0) ? wpre : compose(wpre, up);

    // ---- 3) halo backward walk: exact incoming value, no communication ----
    Pair S = ident();
    int chunkEnd = tile0;
    while (chunkEnd > 0) {
        const int chunkStart = chunkEnd - HCH;   // tile0 % HCH == 0, >= 0
        const int e = chunkStart + tid;
        Pair wnd;
        {
            float x  = in[e];
            float lo = x * k, hi = lo + 1.0f;
            if (e == 0) { lo = x; hi = x; }      // constant p0
            wnd.a = lo; wnd.b = hi;
        }
        // ordered wave tree-reduce; lane 0 = ascending-order wave aggregate
        #pragma unroll
        for (int off = 1; off < 64; off <<= 1) {
            Pair u; u.a = __shfl_down(wnd.a, off); u.b = __shfl_down(wnd.b, off);
            Pair c = compose(wnd, u);
            if (lane + off < 64) wnd = c;
        }
        if (lane == 0) wC[wid] = wnd;
        __syncthreads();
        Pair cagg = wC[0];
        #pragma unroll
        for (int i = 1; i < NW; ++i) cagg = compose(cagg, wC[i]);
        __syncthreads();                         // protect wC for next iter
        S = compose(cagg, S);                    // prepend older chunk
        if (S.a == S.b) break;                   // collapsed: exact
        chunkEnd = chunkStart;
    }
    const float ysrc = med3f(0.0f, S.a, S.b);    // vid 0: med3(0,-inf,inf)=0

    // ---- 4) apply: value-threading, direct coalesced float4 store ---------
    const float ytin = med3f(ysrc, ex.a, ex.b);  // exact incoming value
    if (blockFull) {
        float4 o;
        o.x = med3f(ytin, ta[0], tb[0]);
        o.y = med3f(ytin, ta[1], tb[1]);
        o.z = med3f(ytin, ta[2], tb[2]);
        o.w = med3f(ytin, ta[3], tb[3]);
        *reinterpret_cast<float4*>(out + base) = o;
    } else {
        #pragma unroll
        for (int j = 0; j < EPT; ++j)
            if (base + j < n) out[base + j] = med3f(ytin, ta[j], tb[j]);
    }
}

// ========================== host launcher ==================================
extern "C" void kernel_launch(void* const* d_in, const int* in_sizes, int n_in,
                              void* d_out, int out_size, void* d_ws, size_t ws_size,
                              hipStream_t stream) {
    const float* in   = (const float*)d_in[0];   // [T+1], in[0] = p0
    const float* kptr = (const float*)d_in[1];   // scalar weight
    float* out = (float*)d_out;                  // [T+1]
    const int n  = in_sizes[0];
    const int nb = (n + EPB - 1) / EPB;          // 16385 for T = 2^24

    k_scan<<<nb, TPB, 0, stream>>>(in, kptr, out, n);
}

// Round 14
// 26.170 us; speedup vs baseline: 1.2255x; 1.2255x over previous
//
#include <hip/hip_runtime.h>
#include <math.h>

// y_t = clamp(y_{t-1}, x_t, x_t+1): play operator as associative clamp-scan.
// compose(l, r) = "apply l first, then r". min/max/med3-only => exact =>
// any regrouping is bit-identical (deterministic).
//
// COLLAPSE PROPERTY: composed windows contract and width-0 is absorbing.
// Element 0's window is (p0,p0), so ANY prefix reaching element 0 is
// collapsed. Each block recomputes its exact incoming value from the RAW
// INPUT halo: walk backwards in 256-element chunks, composing chunk
// aggregates until collapse (guaranteed at element 0; typically 1 chunk).
// NO inter-block communication (rounds 2/10/11: cross-XCD sync through
// non-coherent L2s costs 2-6x, fenced or relaxed).
//
// Round-13 lesson: EPT=4 (more blocks, no transpose) regressed -- per-block
// fixed costs dominate. Keep EPT=16; cheapen the transpose with b128 +
// 16B-unit XOR swizzle (both sides spread evenly over 8 bank groups) and
// hide halo latency by prefetching the first chunk at kernel entry.

#define TPB 256
#define EPT 16
#define EPB (TPB * EPT)   // 4096 elements per block -> nb = 4097 for T=2^24
#define NW  (TPB / 64)
#define HCH 256           // halo chunk: 1 element per thread

struct Pair { float a, b; };

__device__ __forceinline__ float med3f(float x, float lo, float hi) {
    return __builtin_amdgcn_fmed3f(x, lo, hi);   // clamp(x, lo, hi), lo<=hi
}
__device__ __forceinline__ Pair compose(Pair l, Pair r) {
    Pair o; o.a = med3f(l.a, r.a, r.b); o.b = med3f(l.b, r.a, r.b); return o;
}
__device__ __forceinline__ Pair ident() {
    Pair p; p.a = -INFINITY; p.b = INFINITY; return p;
}

__global__ __launch_bounds__(TPB)
void k_scan(const float* __restrict__ in, const float* __restrict__ kptr,
            float* __restrict__ out, int n) {
    const int tid  = threadIdx.x, lane = tid & 63, wid = tid >> 6;
    const int vid  = blockIdx.x;
    const int tile0 = vid * EPB;
    const int base  = tile0 + tid * EPT;
    const float k   = kptr[0];
    const bool blockFull = (tile0 + EPB <= n);   // uniform across block

    __shared__ float xpose[EPB];                 // 16 KB transpose buffer
    __shared__ Pair  wS[NW];                     // block-scan wave aggs
    __shared__ Pair  wC[NW];                     // halo-chunk wave aggs

    // ---- 0) prefetch first halo chunk (latency hides under tile phase) ----
    float hx = 0.0f;
    if (tile0 > 0) hx = in[tile0 - HCH + tid];

    // ---- 1) tile load + per-element thread-local inclusive windows --------
    float ta[EPT], tb[EPT];                      // static indexing only
    {
        float a = -INFINITY, b = INFINITY;
        if (blockFull) {
            #pragma unroll
            for (int v = 0; v < EPT / 4; ++v) {
                float4 f = reinterpret_cast<const float4*>(in + base)[v];
                float xv[4] = {f.x, f.y, f.z, f.w};
                #pragma unroll
                for (int jj = 0; jj < 4; ++jj) {
                    float lo = xv[jj] * k, hi = lo + 1.0f;
                    if (v == 0 && jj == 0 && base == 0) { lo = xv[0]; hi = xv[0]; }
                    a = med3f(a, lo, hi);
                    b = med3f(b, lo, hi);
                    ta[4*v+jj] = a; tb[4*v+jj] = b;
                }
            }
        } else {
            #pragma unroll
            for (int j = 0; j < EPT; ++j) {
                if (base + j < n) {
                    float x = in[base + j];
                    float lo = x * k, hi = lo + 1.0f;
                    if (j == 0 && base == 0) { lo = x; hi = x; }
                    a = med3f(a, lo, hi);
                    b = med3f(b, lo, hi);
                }
                ta[j] = a; tb[j] = b;
            }
        }
    }

    // ---- 2) block scan of thread aggregates -> exclusive window ex --------
    Pair w; w.a = ta[EPT - 1]; w.b = tb[EPT - 1];
    #pragma unroll
    for (int off = 1; off < 64; off <<= 1) {
        Pair u; u.a = __shfl_up(w.a, off); u.b = __shfl_up(w.b, off);
        if (lane >= off) w = compose(u, w);
    }
    if (lane == 63) wS[wid] = w;
    __syncthreads();
    Pair wpre = ident();
    #pragma unroll
    for (int i = 0; i < NW; ++i) if (i < wid) wpre = compose(wpre, wS[i]);
    Pair up; up.a = __shfl_up(w.a, 1); up.b = __shfl_up(w.b, 1);
    Pair ex = (lane == 0) ? wpre : compose(wpre, up);

    // ---- 3) halo backward walk (prefetched first chunk) -------------------
    Pair S = ident();
    int chunkEnd = tile0;
    bool first = true;
    while (chunkEnd > 0) {
        const int chunkStart = chunkEnd - HCH;   // tile0 % HCH == 0
        const int e = chunkStart + tid;
        float x = first ? hx : in[e];
        first = false;
        Pair wnd;
        {
            float lo = x * k, hi = lo + 1.0f;
            if (e == 0) { lo = x; hi = x; }      // constant p0
            wnd.a = lo; wnd.b = hi;
        }
        // ordered wave tree-reduce; lane 0 = ascending-order wave aggregate
        #pragma unroll
        for (int off = 1; off < 64; off <<= 1) {
            Pair u; u.a = __shfl_down(wnd.a, off); u.b = __shfl_down(wnd.b, off);
            Pair c = compose(wnd, u);
            if (lane + off < 64) wnd = c;
        }
        if (lane == 0) wC[wid] = wnd;
        __syncthreads();
        Pair cagg = wC[0];
        #pragma unroll
        for (int i = 1; i < NW; ++i) cagg = compose(cagg, wC[i]);
        __syncthreads();                         // protect wC for next iter
        S = compose(cagg, S);                    // prepend older chunk
        if (S.a == S.b) break;                   // collapsed: exact
        chunkEnd = chunkStart;
    }
    const float ysrc = med3f(0.0f, S.a, S.b);    // vid 0: med3(0,-inf,inf)=0

    // ---- 4) apply + b128 swizzled transpose + coalesced store -------------
    const float ytin = med3f(ysrc, ex.a, ex.b);  // exact incoming value
    if (blockFull) {
        // write: unit u = 4*tid+v, swizzled u^=(u>>3)&7 -> lanes spread
        // evenly over all 8 bank groups (checked both sides)
        #pragma unroll
        for (int v = 0; v < EPT / 4; ++v) {
            float4 ov;
            ov.x = med3f(ytin, ta[4*v+0], tb[4*v+0]);
            ov.y = med3f(ytin, ta[4*v+1], tb[4*v+1]);
            ov.z = med3f(ytin, ta[4*v+2], tb[4*v+2]);
            ov.w = med3f(ytin, ta[4*v+3], tb[4*v+3]);
            const unsigned u  = (unsigned)(tid * 4 + v);
            const unsigned us = u ^ ((u >> 3) & 7u);
            *reinterpret_cast<float4*>(&xpose[us * 4]) = ov;
        }
        __syncthreads();
        #pragma unroll
        for (int c4 = 0; c4 < EPT / 4; ++c4) {
            const unsigned u  = (unsigned)(c4 * TPB + tid);
            const unsigned us = u ^ ((u >> 3) & 7u);
            float4 f = *reinterpret_cast<const float4*>(&xpose[us * 4]);
            reinterpret_cast<float4*>(out + tile0)[u] = f;
        }
    } else {
        #pragma unroll
        for (int j = 0; j < EPT; ++j)
            if (base + j < n) out[base + j] = med3f(ytin, ta[j], tb[j]);
    }
}

// ========================== host launcher ==================================
extern "C" void kernel_launch(void* const* d_in, const int* in_sizes, int n_in,
                              void* d_out, int out_size, void* d_ws, size_t ws_size,
                              hipStream_t stream) {
    const float* in   = (const float*)d_in[0];   // [T+1], in[0] = p0
    const float* kptr = (const float*)d_in[1];   // scalar weight
    float* out = (float*)d_out;                  // [T+1]
    const int n  = in_sizes[0];
    const int nb = (n + EPB - 1) / EPB;          // 4097 for T = 2^24

    k_scan<<<nb, TPB, 0, stream>>>(in, kptr, out, n);
}